// Round 13
// baseline (214.768 us; speedup 1.0000x reference)
//
#include <hip/hip_runtime.h>
#include <stdint.h>

typedef __bf16 bf16x8 __attribute__((ext_vector_type(8)));
typedef float floatx4 __attribute__((ext_vector_type(4)));
typedef uint32_t uint32x4 __attribute__((ext_vector_type(4)));

#define GRID_W   15
#define PAD_W    17
#define CELLS    221            // 13*17 padded cells
#define HEXDIM   64
#define NHEX     165
#define OUTC     64
#define KDIM     448
#define CSTRIDE  20             // words per cell per half-buffer (16 data + 4 pad)
#define HBWORDS  (CELLS * CSTRIDE)  // 4420 words = 17,680 B per half-buffer
#define SPB      2              // samples per block
#define NUNITS   (2 * SPB)      // units = (sample, dim-half)
#define HF4      (NHEX * 8)     // 1320 float4 per half-sample

// round-to-nearest-even fp32 -> bf16, packed pair
__device__ __forceinline__ uint32_t pack2bf(float a, float b) {
    union { float f; uint32_t u; } ua, ub;
    ua.f = a; ub.f = b;
    uint32_t ra = (ua.u + 0x7fffu + ((ua.u >> 16) & 1u)) >> 16;
    uint32_t rb = (ub.u + 0x7fffu + ((ub.u >> 16) & 1u)) >> 16;
    return ra | (rb << 16);
}

// ---- prep: W fp32 -> bf16, K reordered h-major ----
// Wbf[o][word r]: r = H*112 + j*16 + w  holds dims {H*32+2w, H*32+2w+1} of neighbor j.
__global__ void wprep_kernel(const float* __restrict__ W, uint32_t* __restrict__ Wbf) {
    int o = blockIdx.x;              // 64 blocks
    int r = threadIdx.x;             // 256 threads, top 32 idle
    if (r < 224) {
        int H = r / 112, rr = r - H * 112;
        int j = rr >> 4, w = rr & 15;
        const float* src = W + o * KDIM + j * 64 + H * 32 + w * 2;
        Wbf[o * 224 + r] = pack2bf(src[0], src[1]);
    }
}

// Operand-swapped MFMA: A = W fragment (o rows), B = x fragment (hex cols).
// C tile is (o = row, hex = col) -> each lane holds 4 consecutive o's for one hex.
__device__ __forceinline__ floatx4 mfma16(uint32x4 a, uint32x4 b, floatx4 c) {
    return __builtin_amdgcn_mfma_f32_16x16x32_bf16(
        __builtin_bit_cast(bf16x8, a), __builtin_bit_cast(bf16x8, b), c, 0, 0, 0);
}

// launch_bounds(512,2): VGPR cap 128 (r7: VGPR=112 no spill; arg 4 capped at 64
// and spilled ~95MB). LDS 35.4KB would allow 4 blocks/CU, VGPR ~112 allows 2.
__global__ __launch_bounds__(512, 2)
void hexconv_kernel(const float* __restrict__ x,
                    const uint32_t* __restrict__ Wbf,
                    const float* __restrict__ bias,
                    float* __restrict__ out, int B)
{
    // rolling half-buffers: 2 x 17,680 B = 35,360 B
    __shared__ __align__(16) uint32_t sx[2 * HBWORDS];

    const int tid  = threadIdx.x;
    const int wave = tid >> 6;
    const int lane = tid & 63;
    const int col  = lane & 15;   // o within tile (A-row) / hex within tile (B/C-col)
    const int kq   = lane >> 4;   // k-quad
    const int og   = wave & 1;    // o-pair: o-tiles og*2, og*2+1
    const int mg   = wave >> 1;   // m-group: m-tiles mg*3 + {0,1,2}

    const uint32_t* w0 = Wbf + (og * 32 + col) * 224 + kq * 4;
    const uint32_t* w1 = w0 + 16 * 224;

    // ---- staging offsets: 3 float4 per thread per half (1320 = 2*512 + 296) ----
    int soff[3], doff[3];
    #pragma unroll
    for (int j = 0; j < 3; ++j) {
        int i  = tid + j * 512;
        int ii = (i < HF4) ? i : 0;
        int n = ii >> 3, dh = ii & 7;
        int y0 = n / GRID_W, x0 = n - y0 * GRID_W;
        int cell = (y0 + 1) * PAD_W + (x0 + 1);
        soff[j] = n * 16 + dh;            // + H*8 at use
        doff[j] = cell * CSTRIDE + dh * 2;
    }
    const bool v2 = tid < (HF4 - 2 * 512);   // 296-thread tail for j=2

    // ---- neighbor bases per m-tile (sample-invariant, hoisted) ----
    const int off0[7] = {-17, -16, -1, 0, 1, 17, 18};
    const int off1[7] = {-18, -17, -1, 0, 1, 16, 17};
    int base3[3], use3[3], valid3[3];
    #pragma unroll
    for (int mt3 = 0; mt3 < 3; ++mt3) {
        int n = (mg * 3 + mt3) * 16 + col;
        bool valid = (n < NHEX);
        int nn = valid ? n : 0;
        int y0 = nn / GRID_W, x0 = nn - y0 * GRID_W;
        base3[mt3]  = (y0 + 1) * PAD_W + (x0 + 1);
        use3[mt3]   = (y0 & 1);
        valid3[mt3] = valid;
    }

    const int s0 = blockIdx.x * SPB;
    const float4* xb = (const float4*)(x + (size_t)s0 * NHEX * HEXDIM);

    // ---- prologue: stage unit 0 = (s0, H=0); zero halos of BOTH buffers ----
    {
        float4 pv0, pv1, pv2;
        if (s0 < B) {
            pv0 = xb[soff[0]];
            pv1 = xb[soff[1]];
            if (v2) pv2 = xb[soff[2]];
        }
        if (tid < 448) {     // 56 halo cells x 4 chunks x 2 buffers
            int t = tid; int buf = t >= 224; t -= buf * 224;
            int c = t >> 2, ch = t & 3;
            int cell;
            if (c < 17)      cell = c;                        // top row 0
            else if (c < 34) cell = 12 * PAD_W + (c - 17);    // bottom row 12
            else if (c < 45) cell = (c - 33) * PAD_W;         // left col, rows 1..11
            else             cell = (c - 44) * PAD_W + 16;    // right col, rows 1..11
            uint32x4 z = {0u, 0u, 0u, 0u};
            *(uint32x4*)(sx + buf * HBWORDS + cell * CSTRIDE + ch * 4) = z;
        }
        if (s0 < B) {
            uint2 p;
            p.x = pack2bf(pv0.x, pv0.y); p.y = pack2bf(pv0.z, pv0.w);
            *(uint2*)(sx + doff[0]) = p;
            p.x = pack2bf(pv1.x, pv1.y); p.y = pack2bf(pv1.z, pv1.w);
            *(uint2*)(sx + doff[1]) = p;
            if (v2) {
                p.x = pack2bf(pv2.x, pv2.y); p.y = pack2bf(pv2.z, pv2.w);
                *(uint2*)(sx + doff[2]) = p;
            }
        }
    }
    __syncthreads();

    // ---- main loop over units. vmcnt FIFO DISCIPLINE (the r9 fix):
    // wf loads (L2) issue FIRST, sv stage loads (HBM) issue AFTER. Since vmcnt
    // retires strictly in issue order, the MFMAs' wf waits are vmcnt(3) --
    // never gated on the HBM stage loads. The only vmcnt(0) is at the ds_write,
    // after ~600cy of ds_read+MFMA has covered most of the sv latency.
    floatx4 acc[3][2];
    #pragma unroll 1
    for (int u = 0; u < NUNITS; ++u) {
        const int s = u >> 1, H = u & 1;
        const bool uval = (s0 + s) < B;
        const bool nval = (u + 1 < NUNITS) && ((s0 + ((u + 1) >> 1)) < B);
        const uint32_t* sb = sx + H * HBWORDS;

        if (H == 0) {
            #pragma unroll
            for (int m = 0; m < 3; ++m) {
                acc[m][0] = (floatx4){0.f, 0.f, 0.f, 0.f};
                acc[m][1] = (floatx4){0.f, 0.f, 0.f, 0.f};
            }
        }

        // (1) preload ALL W fragments for this half into registers (56 VGPRs, L2)
        uint32x4 wfa[7], wfb[7];
        if (uval) {
            const int Hw = H * 112;
            #pragma unroll
            for (int j = 0; j < 7; ++j) {
                wfa[j] = *(const uint32x4*)(w0 + Hw + j * 16);
                wfb[j] = *(const uint32x4*)(w1 + Hw + j * 16);
            }
        }
        __builtin_amdgcn_sched_barrier(0);

        // (2) issue next-unit stage loads AFTER wf in the vmcnt FIFO
        float4 sv0, sv1, sv2;
        if (nval) {
            const float4* xs = xb + (size_t)((u + 1) >> 1) * (NHEX * HEXDIM / 4);
            int hb = ((u + 1) & 1) * 8;
            sv0 = xs[soff[0] + hb];
            sv1 = xs[soff[1] + hb];
            if (v2) sv2 = xs[soff[2] + hb];
        }
        __builtin_amdgcn_sched_barrier(0);

        // (3) compute: ds_read + MFMA only; waits vmcnt(<=3), never on HBM
        if (uval) {
            #pragma unroll
            for (int j = 0; j < 7; ++j) {
                #pragma unroll
                for (int mt3 = 0; mt3 < 3; ++mt3) {
                    if ((mg * 3 + mt3) * 16 < NHEX) {   // wave-uniform; skips dead tile 11
                        int c = valid3[mt3] ? (base3[mt3] + (use3[mt3] ? off0[j] : off1[j]))
                                            : 16;       // cell 16 = halo(0)
                        uint32x4 bv = *(const uint32x4*)(sb + c * CSTRIDE + kq * 4);
                        acc[mt3][0] = mfma16(wfa[j], bv, acc[mt3][0]);
                        acc[mt3][1] = mfma16(wfb[j], bv, acc[mt3][1]);
                    }
                }
            }
        }

        // (4) publish next unit (vmcnt(0) lands here, mostly covered), barrier
        if (u + 1 < NUNITS) {
            if (nval) {
                uint32_t* db = sx + ((u + 1) & 1) * HBWORDS;
                uint2 p;
                p.x = pack2bf(sv0.x, sv0.y); p.y = pack2bf(sv0.z, sv0.w);
                *(uint2*)(db + doff[0]) = p;
                p.x = pack2bf(sv1.x, sv1.y); p.y = pack2bf(sv1.z, sv1.w);
                *(uint2*)(db + doff[1]) = p;
                if (v2) {
                    p.x = pack2bf(sv2.x, sv2.y); p.y = pack2bf(sv2.z, sv2.w);
                    *(uint2*)(db + doff[2]) = p;
                }
            }
            __syncthreads();
        }

        // (5) epilogue after the barrier (overlaps next unit's stage)
        if (H == 1 && uval) {
            float4 b40 = *(const float4*)(bias + og * 32 + kq * 4);
            float4 b41 = *(const float4*)(bias + og * 32 + 16 + kq * 4);
            float* outb = out + (size_t)(s0 + s) * NHEX * OUTC;
            #pragma unroll
            for (int mt3 = 0; mt3 < 3; ++mt3) {
                int n = (mg * 3 + mt3) * 16 + col;
                if (n < NHEX) {
                    float* po = outb + (size_t)n * OUTC + og * 32 + kq * 4;
                    float4 o0, o1;
                    o0.x = acc[mt3][0][0] + b40.x; o0.y = acc[mt3][0][1] + b40.y;
                    o0.z = acc[mt3][0][2] + b40.z; o0.w = acc[mt3][0][3] + b40.w;
                    o1.x = acc[mt3][1][0] + b41.x; o1.y = acc[mt3][1][1] + b41.y;
                    o1.z = acc[mt3][1][2] + b41.z; o1.w = acc[mt3][1][3] + b41.w;
                    *(float4*)po        = o0;   // o = og*32 + kq*4 .. +3
                    *(float4*)(po + 16) = o1;   // o = og*32 + 16 + kq*4 .. +3
                }
            }
        }
    }
}

extern "C" void kernel_launch(void* const* d_in, const int* in_sizes, int n_in,
                              void* d_out, int out_size, void* d_ws, size_t ws_size,
                              hipStream_t stream) {
    const float* x    = (const float*)d_in[0];
    const float* W    = (const float*)d_in[1];
    const float* bias = (const float*)d_in[2];
    float* out        = (float*)d_out;
    uint32_t* Wbf     = (uint32_t*)d_ws;      // 57,344 B of bf16 W (h-major K order)

    wprep_kernel<<<64, 256, 0, stream>>>(W, Wbf);

    int B = in_sizes[0] / (NHEX * HEXDIM);
    int nb = (B + SPB - 1) / SPB;
    hexconv_kernel<<<nb, 512, 0, stream>>>(x, Wbf, bias, out, B);
}

// Round 19
// 202.382 us; speedup vs baseline: 1.0612x; 1.0612x over previous
//
#include <hip/hip_runtime.h>
#include <stdint.h>

typedef __bf16 bf16x8 __attribute__((ext_vector_type(8)));
typedef float floatx4 __attribute__((ext_vector_type(4)));
typedef uint32_t uint32x4 __attribute__((ext_vector_type(4)));

#define GRID_W   15
#define PAD_W    17
#define NHEX     165
#define HEXDIM   64
#define OUTC     64
#define KDIM     448
#define CS       20                    // words per cell per half (16 data + 4 pad)
#define BROWS    6
#define BWORDS   (BROWS * PAD_W * CS)  // 2040 words = 8160 B per wave band

// round-to-nearest-even fp32 -> bf16, packed pair
__device__ __forceinline__ uint32_t pack2bf(float a, float b) {
    union { float f; uint32_t u; } ua, ub;
    ua.f = a; ub.f = b;
    uint32_t ra = (ua.u + 0x7fffu + ((ua.u >> 16) & 1u)) >> 16;
    uint32_t rb = (ub.u + 0x7fffu + ((ub.u >> 16) & 1u)) >> 16;
    return ra | (rb << 16);
}

// Within-wave LDS phase fence: drains the wave's own LDS pipe (RAW/WAR/WAW
// across phases). r17 failed REPLAY-nondeterministically without this --
// sched_barrier alone is compile-time only and inserts no hardware waits.
// sched_barrier(0) on both sides per guide rule #18 (no hoisting across asm).
__device__ __forceinline__ void lds_fence() {
    __builtin_amdgcn_sched_barrier(0);
    asm volatile("s_waitcnt lgkmcnt(0)" ::: "memory");
    __builtin_amdgcn_sched_barrier(0);
}

// ---- prep: W fp32 -> bf16, K reordered h-major (unchanged from r9, verified) ----
// Wbf[o][word r]: r = H*112 + j*16 + w holds dims {H*32+2w, H*32+2w+1} of neighbor j.
__global__ void wprep_kernel(const float* __restrict__ W, uint32_t* __restrict__ Wbf) {
    int o = blockIdx.x;              // 64 blocks
    int r = threadIdx.x;             // 256 threads, top 32 idle
    if (r < 224) {
        int H = r / 112, rr = r - H * 112;
        int j = rr >> 4, w = rr & 15;
        const float* src = W + o * KDIM + j * 64 + H * 32 + w * 2;
        Wbf[o * 224 + r] = pack2bf(src[0], src[1]);
    }
}

// A = W fragment (o rows), B = x fragment (hex cols).
// C: row = o-in-tile = kq*4+reg, col = hex-in-tile = lane&15 (r9-verified mapping).
__device__ __forceinline__ floatx4 mfma16(uint32x4 a, uint32x4 b, floatx4 c) {
    return __builtin_amdgcn_mfma_f32_16x16x32_bf16(
        __builtin_bit_cast(bf16x8, a), __builtin_bit_cast(bf16x8, b), c, 0, 0, 0);
}

// BARRIER-FREE design: 1 wave = (sample, band of 3 m-tiles). 4 independent waves
// per 256-thread block. No __syncthreads anywhere -- within-wave LDS ordering
// via explicit lgkmcnt fences only. TLP across uncoupled waves hides latency.
__global__ __launch_bounds__(256, 4)
void hexconv_kernel(const float* __restrict__ x,
                    const uint32_t* __restrict__ Wbf,
                    const float* __restrict__ bias,
                    float* __restrict__ out, int B)
{
    __shared__ __align__(16) uint32_t sx[4 * BWORDS];   // 32,640 B

    const int tid  = threadIdx.x;
    const int mg   = tid >> 6;        // band id = wave id (m-tiles mg*3+{0,1,2})
    const int lane = tid & 63;
    const int col  = lane & 15;       // hex within tile / W row within tile
    const int kq   = lane >> 4;       // k-quad
    const int s    = blockIdx.x;      // sample

    uint32_t* wb = sx + mg * BWORDS;
    const int prow0 = mg * 3;         // first padded row of this band

    // ---- zero entire band (halo stays zero; interiors overwritten below) ----
    #pragma unroll
    for (int it = 0; it < 8; ++it) {
        int i = lane + it * 64;
        if (i < BWORDS / 4) {
            uint32x4 z = {0u, 0u, 0u, 0u};
            *(uint32x4*)(wb + i * 4) = z;
        }
    }
    lds_fence();    // WAW: zero must land before stage overwrites interiors

    // ---- per-lane m-tile geometry (local band coords) ----
    const int off0[7] = {-17, -16, -1, 0, 1, 17, 18};
    const int off1[7] = {-18, -17, -1, 0, 1, 16, 17};
    int base3[3], use3[3];
    #pragma unroll
    for (int mt3 = 0; mt3 < 3; ++mt3) {
        int n = (mg * 3 + mt3) * 16 + col;
        bool valid = (n < NHEX);
        int nn = valid ? n : 0;
        int y0 = nn / GRID_W, x0 = nn - y0 * GRID_W;
        // local row lr = y0+1-prow0 in [1,4] for valid lanes; neighbors lr 0..5
        int bl = (y0 + 1 - prow0) * PAD_W + (x0 + 1);
        base3[mt3] = valid ? bl : 34;   // 34 = lr2,px0: base+off stays in [16,52] (in-bounds;
                                        // garbage ok -- invalid lanes never stored)
        use3[mt3]  = (y0 & 1);
    }

    const float4* xs = (const float4*)(x + (size_t)s * NHEX * HEXDIM);

    floatx4 acc[3][4];
    #pragma unroll
    for (int m = 0; m < 3; ++m)
        #pragma unroll
        for (int ot = 0; ot < 4; ++ot)
            acc[m][ot] = (floatx4){0.f, 0.f, 0.f, 0.f};

    const uint32_t* wq = Wbf + col * 224 + kq * 4;   // + ot*3584 + H*112 + j*16

    #pragma unroll
    for (int H = 0; H < 2; ++H) {
        // ---- stage half H of the band: rows prow0..prow0+5 that carry real hexes ----
        #pragma unroll
        for (int r = 0; r < BROWS; ++r) {
            int y0 = prow0 + r - 1;             // wave-uniform
            if (y0 >= 0 && y0 <= 10) {
                #pragma unroll
                for (int it = 0; it < 2; ++it) {
                    int i = lane + it * 64;     // 120 f4 per row-half
                    if (i < 120) {
                        int nr = i >> 3, d = i & 7;   // hex-in-row, f4-in-half
                        float4 v = xs[(y0 * GRID_W + nr) * 16 + H * 8 + d];
                        uint2 p;
                        p.x = pack2bf(v.x, v.y); p.y = pack2bf(v.z, v.w);
                        *(uint2*)(wb + (r * PAD_W + nr + 1) * CS + d * 2) = p;
                    }
                }
            }
        }
        lds_fence();    // RAW: stage writes (all lanes) land before compute reads

        // ---- compute half H: 7 j-slices x 3 m-tiles x 4 o-tiles ----
        #pragma unroll
        for (int j = 0; j < 7; ++j) {
            uint32x4 wf0 = *(const uint32x4*)(wq +      0 + H * 112 + j * 16);
            uint32x4 wf1 = *(const uint32x4*)(wq +   3584 + H * 112 + j * 16);
            uint32x4 wf2 = *(const uint32x4*)(wq +   7168 + H * 112 + j * 16);
            uint32x4 wf3 = *(const uint32x4*)(wq +  10752 + H * 112 + j * 16);
            #pragma unroll
            for (int mt3 = 0; mt3 < 3; ++mt3) {
                if ((mg * 3 + mt3) * 16 < NHEX) {   // wave-uniform; skips dead tile 11
                    int c = base3[mt3] + (use3[mt3] ? off0[j] : off1[j]);
                    uint32x4 bv = *(const uint32x4*)(wb + c * CS + kq * 4);
                    acc[mt3][0] = mfma16(wf0, bv, acc[mt3][0]);
                    acc[mt3][1] = mfma16(wf1, bv, acc[mt3][1]);
                    acc[mt3][2] = mfma16(wf2, bv, acc[mt3][2]);
                    acc[mt3][3] = mfma16(wf3, bv, acc[mt3][3]);
                }
            }
        }
        lds_fence();    // WAR: compute-H reads drained before stage-H+1 overwrites
    }

    // ---- epilogue: lane holds o = ot*16 + kq*4 + 0..3 for hex n -> float4 stores ----
    float* outb = out + (size_t)s * NHEX * OUTC;
    float4 b4[4];
    #pragma unroll
    for (int ot = 0; ot < 4; ++ot)
        b4[ot] = *(const float4*)(bias + ot * 16 + kq * 4);
    #pragma unroll
    for (int mt3 = 0; mt3 < 3; ++mt3) {
        int n = (mg * 3 + mt3) * 16 + col;
        if (n < NHEX) {
            float* po = outb + (size_t)n * OUTC + kq * 4;
            #pragma unroll
            for (int ot = 0; ot < 4; ++ot) {
                float4 o4;
                o4.x = acc[mt3][ot][0] + b4[ot].x;
                o4.y = acc[mt3][ot][1] + b4[ot].y;
                o4.z = acc[mt3][ot][2] + b4[ot].z;
                o4.w = acc[mt3][ot][3] + b4[ot].w;
                *(float4*)(po + ot * 16) = o4;
            }
        }
    }
}

extern "C" void kernel_launch(void* const* d_in, const int* in_sizes, int n_in,
                              void* d_out, int out_size, void* d_ws, size_t ws_size,
                              hipStream_t stream) {
    const float* x    = (const float*)d_in[0];
    const float* W    = (const float*)d_in[1];
    const float* bias = (const float*)d_in[2];
    float* out        = (float*)d_out;
    uint32_t* Wbf     = (uint32_t*)d_ws;      // 57,344 B of bf16 W (h-major K order)

    wprep_kernel<<<64, 256, 0, stream>>>(W, Wbf);

    int B = in_sizes[0] / (NHEX * HEXDIM);
    hexconv_kernel<<<B, 256, 0, stream>>>(x, Wbf, bias, out, B);
}